// Round 14
// baseline (1052.235 us; speedup 1.0000x reference)
//
#include <hip/hip_runtime.h>
#include <stdint.h>

#define NBATCH 32
#define NNODE  400
#define NN     12800
#define NE     204800
#define EPE    217600      // NE + NN self loops
#define DD     200
#define NETYPE 38
#define NCOMBO 624         // 39*16
#define HSZ    1024
#define SEQQ   512
#define NL     5
#define ACH    128         // aggr edge-chunk staged in LDS

__device__ __forceinline__ unsigned short f2bf(float x){
  uint32_t u = __float_as_uint(x);
  uint32_t r = (u + 0x7fffu + ((u>>16)&1u)) >> 16;   // RNE
  return (unsigned short)r;
}
__device__ __forceinline__ float bf2f(unsigned short b){
  return __uint_as_float(((uint32_t)b)<<16);
}

// ---------------- threefry / noise ----------------
__device__ __forceinline__ uint32_t rotl32(uint32_t x, uint32_t d){ return (x<<d)|(x>>(32u-d)); }

__device__ void tf2x32(uint32_t k0, uint32_t k1, uint32_t x0, uint32_t x1,
                       uint32_t* o0, uint32_t* o1){
  uint32_t ks0=k0, ks1=k1, ks2=k0^k1^0x1BD11BDAu;
  uint32_t ks[3]={ks0,ks1,ks2};
  x0 += ks0; x1 += ks1;
  const uint32_t rotA[4]={13,15,26,6};
  const uint32_t rotB[4]={17,29,16,24};
  #pragma unroll
  for (int i=0;i<5;i++){
    const uint32_t* r = (i&1)? rotB : rotA;
    #pragma unroll
    for (int j=0;j<4;j++){ x0 += x1; x1 = rotl32(x1, r[j]); x1 ^= x0; }
    x0 += ks[(i+1)%3];
    x1 += ks[(i+2)%3] + (uint32_t)(i+1);
  }
  *o0=x0; *o1=x1;
}

__global__ void k_noise(float* noise){
  int i = blockIdx.x*256+threadIdx.x;
  if (i >= NL*NN) return;
  int l = i / NN, j = i % NN;
  uint32_t k0,k1,o0,o1,bits;
  tf2x32(0u,123u,0u,(uint32_t)l,&k0,&k1);          // fold_in(key(123), l)
  tf2x32(k0,k1,0u,(uint32_t)j,&o0,&o1);            // partitionable path
  bits = o0 ^ o1;
  uint32_t fb = (bits>>9) | 0x3f800000u;
  float f = __uint_as_float(fb) - 1.0f;            // [0,1)
  const float minv = -0.99999994039535522461f;     // -1 + 2^-24
  float u = fmaxf(minv, f*2.0f + minv);
  float s = (u>0.f)?1.f:((u<0.f)?-1.f:0.f);
  noise[i] = s*log1pf(-fabsf(u));
}

// ---------------- graph build ----------------
__global__ void k_edges(const int* eidx, int* outdeg, int* indeg){
  int e = blockIdx.x*256+threadIdx.x; if (e>=EPE) return;
  int s,dv;
  if (e < NE){ s = eidx[e]; dv = eidx[NE+e]; } else { s = dv = e-NE; }
  atomicAdd(&outdeg[s],1); atomicAdd(&indeg[dv],1);
}

// parallel exclusive scan (1024 threads, 13 items each; Hillis-Steele in LDS)
__global__ void k_scan(const int* outdeg, const int* indeg, int* sstart, int* dstart){
  __shared__ int buf[2][1024];
  for (int which=0; which<2; ++which){
    const int* a = which? indeg : outdeg;
    int* o = which? dstart : sstart;
    int t = threadIdx.x;
    int c0 = t*13;
    int s = 0;
    for (int i=c0;i<c0+13;i++) if (i<NN) s += a[i];
    __syncthreads();
    buf[0][t]=s; __syncthreads();
    int cur=0;
    #pragma unroll
    for (int off=1; off<1024; off<<=1){
      int v = buf[cur][t];
      if (t>=off) v += buf[cur][t-off];
      buf[cur^1][t]=v; cur^=1; __syncthreads();
    }
    int run = buf[cur][t] - s;   // exclusive prefix
    for (int i=c0;i<c0+13;i++) if (i<NN){ o[i]=run; run+=a[i]; }
    if (t==0) o[NN]=EPE;
  }
}

__global__ void k_scatter(const int* eidx, const int* etype, const int* ntype,
                          const int* sstart, const int* dstart, int* sfill, int* dfill,
                          int* s_dst, int* s_combo, int* d_src, int* d_combo, int* s_dpos){
  int e = blockIdx.x*256+threadIdx.x; if (e>=EPE) return;
  int s,dv,et;
  if (e<NE){ s=eidx[e]; dv=eidx[NE+e]; et=etype[e]; } else { s=dv=e-NE; et=NETYPE; }
  int c = et*16 + ntype[s]*4 + ntype[dv];
  int p = sstart[s] + atomicAdd(&sfill[s],1);
  s_dst[p]=dv; s_combo[p]=c;
  int q = dstart[dv] + atomicAdd(&dfill[dv],1);
  d_src[q]=s; d_combo[q]=c; s_dpos[p]=q;
}

// ---------------- edge encoder hidden (one-hot -> rows of We1) ----------------
__global__ void k_ehid(const float* We1, const float* be1, float* ehid){
  int i = blockIdx.x*256+threadIdx.x; if (i>=NCOMBO*DD) return;
  int c = i/DD, d = i%DD;
  int et=c>>4, ht=(c>>2)&3, tt=c&3;
  float v = We1[et*DD+d] + We1[(39+ht)*DD+d] + We1[(43+tt)*DD+d] + be1[d];
  ehid[i] = fmaxf(v,0.f);
}

// ---------------- bf16 A-matrix conversions (once per call) ----------------
__global__ void k_cvt_xcat(const float* X, const float* nfe, unsigned short* xbf){
  int i=blockIdx.x*256+threadIdx.x; if (i>=NN*448) return;
  int n=i/448, d=i%448;
  float v = (d<200)? X[(size_t)n*200+d] : (d<400)? nfe[(size_t)n*200+(d-200)] : 0.f;
  xbf[i] = f2bf(v);
}
__global__ void k_cvt_nfe(const float* nfe, unsigned short* nbf){
  int i=blockIdx.x*256+threadIdx.x; if (i>=NN*224) return;
  int n=i/224, d=i%224;
  nbf[i] = (d<200)? f2bf(nfe[(size_t)n*200+d]) : 0;
}
// fp32 -> bf16 flat copy
__global__ void k_cvt_flat(const float* src, unsigned short* dst, int n){
  int i=blockIdx.x*256+threadIdx.x; if (i>=n) return;
  dst[i] = f2bf(src[i]);
}

// ---------------- weight swizzle: fp32 [Ksrc x 200] -> bf16 [(Kpad/8) x 256 x 8] ----------------
struct WJob { const float* src; unsigned short* dst; int Ksrc; int Kpad; };
struct WArgs { WJob j[26]; };
__global__ void k_wswz(WArgs a){
  WJob jb = a.j[blockIdx.z];
  int i = blockIdx.x*256+threadIdx.x;
  if (i >= jb.Kpad*256) return;
  int k = i>>8, n = i&255;
  unsigned short v = 0;
  if (k<jb.Ksrc && n<200) v = f2bf(jb.src[(size_t)k*200+n]);
  jb.dst[(((size_t)(k>>3))*256 + n)*8 + (k&7)] = v;
}

typedef __attribute__((ext_vector_type(8))) short bf16x8;
typedef __attribute__((ext_vector_type(4))) float f32x4;

// ---------------- MFMA bf16 GEMM: C = A(bf16,MxKP) @ B(swz,KP x 256) ----------------
// KP is a compile-time template parameter -> K-loop fully unrolled -> all loads
// issue up-front (MLP hides L2 latency; the runtime-K version was latency-bound
// at MfmaUtil 8%). XCD-aware 1D grid: blocks sharing the same 128 A-rows get the
// same bid%8 -> same XCD L2.
struct MJob { const unsigned short* A; const unsigned short* B; const float* bias;
              float* C; unsigned short* Cbf; const float* r1v; const float* r1m;
              int relu; float scale; int gelu; int cbfs; };
struct MArgs { int nj; MJob j[3]; };

template<int KP>
__global__ __launch_bounds__(256) void k_mgemm(MArgs g){
  const int G = 4*g.nj;
  int bid = blockIdx.x;
  int xcd = bid & 7;
  int t   = bid >> 3;
  int grp = t % G;
  int yhi = t / G;
  int y   = xcd + 8*yhi;
  if (y >= 100) return;
  const int ni = grp & 3;
  const int zi = grp >> 2;
  const MJob jb = g.j[zi];
  const int lane = threadIdx.x&63, w = threadIdx.x>>6;
  const int lr = lane&15, lk = lane>>4;
  const int m0 = y*128 + w*32;
  const int n0 = ni*64;
  f32x4 acc[2][4] = {};
  const unsigned short* a0 = jb.A + (size_t)(m0+lr)*KP + lk*8;
  const unsigned short* a1 = a0 + (size_t)16*KP;
  #pragma unroll
  for (int ks=0; ks<KP; ks+=32){
    bf16x8 af0 = *(const bf16x8*)(a0 + ks);
    bf16x8 af1 = *(const bf16x8*)(a1 + ks);
    const unsigned short* bb = jb.B + (((size_t)(ks>>3) + lk)*256 + n0 + lr)*8;
    bf16x8 b0 = *(const bf16x8*)(bb);
    bf16x8 b1 = *(const bf16x8*)(bb + 128);
    bf16x8 b2 = *(const bf16x8*)(bb + 256);
    bf16x8 b3 = *(const bf16x8*)(bb + 384);
    acc[0][0]=__builtin_amdgcn_mfma_f32_16x16x32_bf16(af0,b0,acc[0][0],0,0,0);
    acc[0][1]=__builtin_amdgcn_mfma_f32_16x16x32_bf16(af0,b1,acc[0][1],0,0,0);
    acc[0][2]=__builtin_amdgcn_mfma_f32_16x16x32_bf16(af0,b2,acc[0][2],0,0,0);
    acc[0][3]=__builtin_amdgcn_mfma_f32_16x16x32_bf16(af0,b3,acc[0][3],0,0,0);
    acc[1][0]=__builtin_amdgcn_mfma_f32_16x16x32_bf16(af1,b0,acc[1][0],0,0,0);
    acc[1][1]=__builtin_amdgcn_mfma_f32_16x16x32_bf16(af1,b1,acc[1][1],0,0,0);
    acc[1][2]=__builtin_amdgcn_mfma_f32_16x16x32_bf16(af1,b2,acc[1][2],0,0,0);
    acc[1][3]=__builtin_amdgcn_mfma_f32_16x16x32_bf16(af1,b3,acc[1][3],0,0,0);
  }
  #pragma unroll
  for (int mt=0; mt<2; ++mt){
    int mbase = m0 + mt*16 + lk*4;
    #pragma unroll
    for (int nt=0; nt<4; ++nt){
      int n = n0 + nt*16 + lr;
      #pragma unroll
      for (int r=0;r<4;r++){
        int m = mbase + r;
        float v = acc[mt][nt][r];
        if (n < 200){
          if (jb.r1v)  v += jb.r1v[m]*jb.r1m[(size_t)(m/NNODE)*200 + n];
          if (jb.bias) v += jb.bias[n];
          v *= jb.scale;
          if (jb.relu) v = fmaxf(v, 0.f);
          if (jb.C)    jb.C[(size_t)m*200 + n] = v;
          if (jb.Cbf){
            float o = jb.gelu? 0.5f*v*(1.0f+erff(v*0.70710678118654752440f)) : v;
            jb.Cbf[(size_t)m*jb.cbfs + n] = f2bf(o);
          }
        } else if (jb.Cbf && jb.cbfs==224 && n < 224){
          jb.Cbf[(size_t)m*224 + n] = 0;
        }
      }
    }
  }
}

// ---------------- small-M fp32 GEMM, K-sliced: part + reduce ----------------
struct RJob { const float* A; const float* W; const float* bias; float* C; int K; size_t lda; };
struct RArgs { RJob j[12]; float* part; int NS; int Kc; };
__global__ __launch_bounds__(256) void k_rowpart(RArgs a){
  RJob jb = a.j[blockIdx.z];
  int m = blockIdx.x, s = blockIdx.y;
  int k0 = s*a.Kc, k1 = k0 + a.Kc; if (k1 > jb.K) k1 = jb.K;
  int kc = k1 - k0;
  __shared__ float row[128];
  const float* ap = jb.A + (size_t)m*jb.lda + k0;
  for (int k=threadIdx.x; k<kc; k+=256) row[k]=ap[k];
  __syncthreads();
  int n = threadIdx.x;
  if (n < 200){
    float acc = 0.f;
    const float* wp = jb.W + (size_t)k0*200 + n;
    for (int kk=0; kk<kc; ++kk) acc += row[kk]*wp[(size_t)kk*200];
    a.part[(((size_t)blockIdx.z*32 + m)*8 + s)*200 + n] = acc;
  }
}
__global__ __launch_bounds__(256) void k_rowred(RArgs a){
  RJob jb = a.j[blockIdx.z];
  int m = blockIdx.x, n = threadIdx.x;
  if (n >= 200) return;
  float acc = jb.bias? jb.bias[n] : 0.f;
  for (int s=0; s<a.NS; ++s) acc += a.part[(((size_t)blockIdx.z*32 + m)*8 + s)*200 + n];
  jb.C[(size_t)m*200+n] = acc;
}

// ---------------- generic fp32 GEMM (M=624 edge-table jobs) ----------------
struct Job {
  const float* A; const float* W; const float* bias; float* C;
  const float* r1v; const float* r1m; int relu;
};
struct GArgs { int M,N,K,lda; Job j[12]; };

#define BMT 64
#define BNT 64
#define BKT 16

__global__ __launch_bounds__(256) void k_gemm(GArgs g){
  const Job jb = g.j[blockIdx.z];
  const int m0 = blockIdx.y*BMT, n0 = blockIdx.x*BNT;
  __shared__ float As[BKT][BMT+4];
  __shared__ float Bs[BKT][BNT+4];
  float acc[4][4]={};
  const int t = threadIdx.x;
  const int tx = t & 15, ty = t >> 4;
  for (int k0=0; k0<g.K; k0+=BKT){
    {
      int r = t>>2, cq = t&3;
      int m = m0+r, k = k0+cq*4;
      float4 v = make_float4(0.f,0.f,0.f,0.f);
      if (m < g.M && k < g.K){
        if (k+3 < g.K) v = *(const float4*)(jb.A + (size_t)m*g.lda + k);
        else {
          const float* ap = jb.A + (size_t)m*g.lda;
          float tm[4]={0.f,0.f,0.f,0.f};
          for (int qq=0;qq<4;qq++) if (k+qq<g.K) tm[qq]=ap[k+qq];
          v = make_float4(tm[0],tm[1],tm[2],tm[3]);
        }
      }
      As[cq*4+0][r]=v.x; As[cq*4+1][r]=v.y; As[cq*4+2][r]=v.z; As[cq*4+3][r]=v.w;
    }
    {
      int r = t>>4, cq = t&15;
      int k = k0+r, n = n0+cq*4;
      float4 v = make_float4(0.f,0.f,0.f,0.f);
      if (k < g.K && n < g.N){
        if (n+3 < g.N) v = *(const float4*)(jb.W + (size_t)k*g.N + n);
        else { const float* wp = jb.W + (size_t)k*g.N;
          float tm[4]={0.f,0.f,0.f,0.f};
          for (int qq=0;qq<4;qq++) if (n+qq<g.N) tm[qq]=wp[n+qq];
          v = make_float4(tm[0],tm[1],tm[2],tm[3]); }
      }
      Bs[r][cq*4+0]=v.x; Bs[r][cq*4+1]=v.y; Bs[r][cq*4+2]=v.z; Bs[r][cq*4+3]=v.w;
    }
    __syncthreads();
    int kend = g.K-k0; if (kend>BKT) kend=BKT;
    for (int kk=0;kk<kend;kk++){
      float4 av = *(const float4*)&As[kk][ty*4];
      float4 bv = *(const float4*)&Bs[kk][tx*4];
      float a[4]={av.x,av.y,av.z,av.w};
      float b[4]={bv.x,bv.y,bv.z,bv.w};
      #pragma unroll
      for (int i=0;i<4;i++){
        #pragma unroll
        for (int jq=0;jq<4;jq++) acc[i][jq] += a[i]*b[jq];
      }
    }
    __syncthreads();
  }
  #pragma unroll
  for (int i=0;i<4;i++){
    int m = m0+ty*4+i; if (m>=g.M) continue;
    int bidx = m / NNODE;
    #pragma unroll
    for (int jq=0;jq<4;jq++){
      int n = n0+tx*4+jq; if (n>=g.N) continue;
      float v = acc[i][jq];
      if (jb.bias) v += jb.bias[n];
      if (jb.r1v)  v += jb.r1v[m]*jb.r1m[(size_t)bidx*g.N + n];
      if (jb.relu) v = fmaxf(v,0.f);
      jb.C[(size_t)m*g.N+n] = v;
    }
  }
}

// ---------------- per-node prep: ps[h] = sum_d qv*ak (bf16 tables) ----------------
__global__ void k_prep(const unsigned short* qv, const unsigned short* ak, float* ps){
  int wid = threadIdx.x>>6, lane = threadIdx.x&63;
  int n = blockIdx.x*4 + wid; if (n>=NN) return;
  float acch[4]={0.f,0.f,0.f,0.f};
  if (lane < 25){
    bf16x8 q = *(const bf16x8*)(qv + (size_t)n*200 + lane*8);
    bf16x8 a = *(const bf16x8*)(ak + (size_t)n*200 + lane*8);
    #pragma unroll
    for (int j=0;j<8;j++){
      int d = lane*8+j;
      int hd = (d>=50)+(d>=100)+(d>=150);
      float p = bf2f((unsigned short)q[j])*bf2f((unsigned short)a[j]);
      #pragma unroll
      for (int h=0;h<4;h++) acch[h] += (hd==h)? p : 0.f;
    }
  }
  for (int off=1; off<64; off<<=1){
    #pragma unroll
    for (int h=0;h<4;h++) acch[h] += __shfl_xor(acch[h], off);
  }
  if (lane==0){
    #pragma unroll
    for (int h=0;h<4;h++) ps[n*4+h]=acch[h];
  }
}

// ---------------- per-edge scores: 4 lanes per edge, bf16 qv/Bk gathers ----------------
__global__ __launch_bounds__(256) void k_score(const int* s_dst, const int* s_combo,
                        const unsigned short* qv, const unsigned short* Bk,
                        const float* ps, float* scores){
  int p = blockIdx.x*64 + (threadIdx.x>>2);
  if (p>=EPE) return;
  int sub = threadIdx.x&3;
  int dv = s_dst[p], c = s_combo[p];
  const unsigned short* qr = qv + (size_t)dv*200;
  const unsigned short* br = Bk + (size_t)c*200;
  float acc[4]={0.f,0.f,0.f,0.f};
  #pragma unroll
  for (int i=0;i<7;i++){
    int ch = sub + 4*i;
    if (ch < 25){
      bf16x8 q = *(const bf16x8*)(qr + ch*8);
      bf16x8 b = *(const bf16x8*)(br + ch*8);
      #pragma unroll
      for (int j=0;j<8;j++){
        int d = ch*8+j;
        int hd = (d>=50)+(d>=100)+(d>=150);
        float pr = bf2f((unsigned short)q[j])*bf2f((unsigned short)b[j]);
        #pragma unroll
        for (int h=0;h<4;h++) acc[h] += (hd==h)? pr : 0.f;
      }
    }
  }
  #pragma unroll
  for (int off=1; off<4; off<<=1){
    #pragma unroll
    for (int h=0;h<4;h++) acc[h] += __shfl_xor(acc[h], off);
  }
  scores[(size_t)p*4+sub] = ps[dv*4+sub] + acc[sub];
}

// ---------------- segment softmax over src; alpha scattered to dst-order ----------------
__global__ void k_softmax(const int* sstart, const int* s_dpos, const float* scores, float* alpha_d){
  int n = blockIdx.x;
  int st = sstart[n], en = sstart[n+1];
  int cnt = en-st;
  int t = threadIdx.x;
  float mx = -3.402823466e38f;
  for (int i=t; i<cnt*4; i+=64) mx = fmaxf(mx, scores[(size_t)(st+(i>>2))*4 + (i&3)]);
  for (int off=4; off<64; off<<=1) mx = fmaxf(mx, __shfl_xor(mx,off));
  float sm=0.f;
  for (int i=t; i<cnt*4; i+=64) sm += expf(scores[(size_t)(st+(i>>2))*4 + (i&3)] - mx);
  for (int off=4; off<64; off<<=1) sm += __shfl_xor(sm,off);
  float scale = (float)cnt / (sm + 1e-16f);
  for (int i=t; i<cnt*4; i+=64){
    int p = st+(i>>2), h = i&3;
    float a = expf(scores[(size_t)p*4+h]-mx)*scale;
    alpha_d[(size_t)s_dpos[p]*4+h] = a;
  }
}

// ---------------- aggregate to dst: LDS-staged indices+alpha, 4 waves/node ----------------
__global__ __launch_bounds__(256) void k_aggr(const int* dstart, const int* d_src, const int* d_combo,
                       const float* alpha_d,
                       const unsigned short* Am, const unsigned short* Bm,
                       unsigned short* aggr_bf){
  __shared__ float red[4][200];
  __shared__ float s_al[ACH*4];
  __shared__ int   s_s[ACH], s_c[ACH];
  int v = blockIdx.x;
  int w = threadIdx.x>>6, lane = threadIdx.x&63;
  int st=dstart[v], en=dstart[v+1];
  float acc[8]={0.f,0.f,0.f,0.f,0.f,0.f,0.f,0.f};
  int h[8];
  #pragma unroll
  for (int j=0;j<8;j++) h[j] = (lane*8+j)/50;     // valid for lane<25
  for (int c0=st; c0<en; c0+=ACH){
    int cnt = en-c0; if (cnt>ACH) cnt=ACH;
    __syncthreads();
    for (int i=threadIdx.x; i<cnt; i+=256){ s_s[i]=d_src[c0+i]; s_c[i]=d_combo[c0+i]; }
    for (int i=threadIdx.x; i<cnt*4; i+=256){ s_al[i]=alpha_d[(size_t)c0*4+i]; }
    __syncthreads();
    if (lane < 25){
      for (int q=w; q<cnt; q+=4){
        int s=s_s[q], c=s_c[q];
        bf16x8 am = *(const bf16x8*)(Am + (size_t)s*200 + lane*8);
        bf16x8 bm = *(const bf16x8*)(Bm + (size_t)c*200 + lane*8);
        #pragma unroll
        for (int j=0;j<8;j++){
          float a = s_al[q*4+h[j]];
          acc[j] += a*(bf2f((unsigned short)am[j]) + bf2f((unsigned short)bm[j]));
        }
      }
    }
  }
  if (lane < 25){
    #pragma unroll
    for (int j=0;j<8;j++) red[w][lane*8+j]=acc[j];
  }
  __syncthreads();
  int d = threadIdx.x;
  if (d < 200){
    float r = red[0][d]+red[1][d]+red[2][d]+red[3][d];
    aggr_bf[(size_t)v*224+d]=f2bf(r);
  } else if (d < 224){
    aggr_bf[(size_t)v*224+d]=0;
  }
}

// ---------------- sensitivity: max ||out||^2 ----------------
__global__ void k_sens(const float* out, float* sens2, int l){
  __shared__ float smax[4];
  int wid = threadIdx.x>>6, lane = threadIdx.x&63;
  int gw = blockIdx.x*4 + wid;
  float mx = 0.f;
  for (int n = gw; n < NN; n += 256){
    const float4* row = (const float4*)(out + (size_t)n*DD);
    float ss = 0.f;
    if (lane < 50){ float4 v = row[lane]; ss = v.x*v.x + v.y*v.y + v.z*v.z + v.w*v.w; }
    for (int off=1; off<64; off<<=1) ss += __shfl_xor(ss, off);
    mx = fmaxf(mx, ss);
  }
  if (lane==0) smax[wid] = mx;
  __syncthreads();
  if (threadIdx.x==0){
    float m = fmaxf(fmaxf(smax[0],smax[1]),fmaxf(smax[2],smax[3]));
    atomicMax((int*)&sens2[l], __float_as_int(m));
  }
}

// ---------------- attention (Q in bf16) ----------------
__global__ void k_att(const unsigned short* Qb, const float* Katt, const float* Vatt,
                      const float* sens2, const float* noise, int l,
                      float* att, float* outX){
  int wid=threadIdx.x>>6, lane=threadIdx.x&63;
  int n=blockIdx.x*4+wid; if (n>=NN) return;
  int b=n/NNODE;
  float qq=0.f, qk=0.f;
  for (int d=lane; d<DD; d+=64){
    float q=bf2f(Qb[(size_t)n*200+d]);
    qq += q*q; qk += q*Katt[b*DD+d];
  }
  for (int off=1;off<64;off<<=1){ qq+=__shfl_xor(qq,off); qk+=__shfl_xor(qk,off); }
  float nrm = fmaxf(sqrtf(qq), 1e-12f);
  float a = (qk/nrm) * 0.07071067811865475244f;    // 1/sqrt(200)
  a += 4.0f*sqrtf(sens2[l]) * noise[(size_t)l*NN + n];
  if (lane==0) att[n]=a;
  if (outX){
    for (int d=lane; d<DD; d+=64) outX[(size_t)n*DD+d] = a*Vatt[b*DD+d];
  }
}

// ---------------- host ----------------
static inline Job mkjob(const float* A, const float* W, const float* bias, float* C,
                        const float* r1v, const float* r1m, int relu){
  Job j; j.A=A; j.W=W; j.bias=bias; j.C=C; j.r1v=r1v; j.r1m=r1m; j.relu=relu; return j;
}

static inline void gemm_launch(hipStream_t stream, int M,int N,int K,int lda,
                               const Job* jobs, int nj){
  GArgs g; g.M=M; g.N=N; g.K=K; g.lda=lda;
  for (int i=0;i<nj;i++) g.j[i]=jobs[i];
  for (int i=nj;i<12;i++) g.j[i]=jobs[0];
  dim3 grid((N+BNT-1)/BNT,(M+BMT-1)/BMT,nj);
  k_gemm<<<grid,256,0,stream>>>(g);
}

static inline RJob mkrjob(const float* A, const float* W, const float* bias, float* C,
                          int K, size_t lda){
  RJob j; j.A=A; j.W=W; j.bias=bias; j.C=C; j.K=K; j.lda=lda; return j;
}

static inline void rgemm_launch(hipStream_t stream, const RJob* jobs, int nj,
                                float* part, int NS, int Kc){
  RArgs a;
  for (int i=0;i<nj;i++) a.j[i]=jobs[i];
  for (int i=nj;i<12;i++) a.j[i]=jobs[0];
  a.part = part; a.NS = NS; a.Kc = Kc;
  k_rowpart<<<dim3(NBATCH,NS,nj),256,0,stream>>>(a);
  k_rowred <<<dim3(NBATCH,1,nj),256,0,stream>>>(a);
}

static inline MJob mkmjob(const unsigned short* A, const unsigned short* B, const float* bias,
                          float* C, unsigned short* Cbf, const float* r1v, const float* r1m,
                          int relu, float scale, int gelu, int cbfs){
  MJob j; j.A=A; j.B=B; j.bias=bias; j.C=C; j.Cbf=Cbf; j.r1v=r1v; j.r1m=r1m;
  j.relu=relu; j.scale=scale; j.gelu=gelu; j.cbfs=cbfs; return j;
}

static inline void mgemm_launch(hipStream_t stream, int Kpad, const MJob* jobs, int nj){
  MArgs a; a.nj=nj;
  for (int i=0;i<nj;i++) a.j[i]=jobs[i];
  for (int i=nj;i<3;i++) a.j[i]=jobs[0];
  int nblk = 8 * (4*nj) * 13;   // y groups of 8, 13 groups cover y<100
  if (Kpad == 448) k_mgemm<448><<<nblk,256,0,stream>>>(a);
  else             k_mgemm<224><<<nblk,256,0,stream>>>(a);
}

extern "C" void kernel_launch(void* const* d_in, const int* in_sizes, int n_in,
                              void* d_out, int out_size, void* d_ws, size_t ws_size,
                              hipStream_t stream){
  const float* hs    = (const float*)d_in[0];
  const float* X     = (const float*)d_in[1];
  const float* nfe   = (const float*)d_in[2];
  const int*   eidx  = (const int*)d_in[3];
  const int*   etype = (const int*)d_in[4];
  const int*   ntype = (const int*)d_in[5];
  const float* We1   = (const float*)d_in[7];
  const float* be1   = (const float*)d_in[8];
  const float* We2   = (const float*)d_in[9];
  const float* be2   = (const float*)d_in[10];
  const float* Wkey  = (const float*)d_in[11];
  const float* bkey  = (const float*)d_in[12];
  const float* Wmsg  = (const float*)d_in[13];
  const float* bmsg  = (const float*)d_in[14];
  const float* Wqry  = (const float*)d_in[15];
  const float* bqry  = (const float*)d_in[16];
  const float* Wm1   = (const float*)d_in[17];
  const float* bm1   = (const float*)d_in[18];
  const float* Wm2   = (const float*)d_in[19];
  const float* bm2   = (const float*)d_in[20];
  const float* Wq_att= (const float*)d_in[21];
  const float* bq_att= (const float*)d_in[22];
  const float* Wk_att= (const float*)d_in[23];
  const float* bk_att= (const float*)d_in[24];
  const float* Wv_att= (const float*)d_in[25];
  const float* bv_att= (const float*)d_in[26];
  const float* Wproj = (const float*)d_in[27];
  const float* bproj = (const float*)d_in[28];
  float* outp = (float*)d_out;

  char* cur = (char*)d_ws;
  auto allocf = [&](size_t n)->float*{ float* p=(float*)cur; cur += ((n*4+255)/256)*256; return p; };
  auto alloci = [&](size_t n)->int*  { int*   p=(int*)cur;   cur += ((n*4+255)/256)*256; return p; };
  auto allocb = [&](size_t n)->unsigned short*{ unsigned short* p=(unsigned short*)cur; cur += ((n*2+255)/256)*256; return p; };

  float* noise  = allocf((size_t)NL*NN);
  float* ehid   = allocf((size_t)NCOMBO*DD);
  float* eemb   = allocf((size_t)NCOMBO*DD);
  float* Bk     = allocf((size_t)NL*NCOMBO*DD);
  float* Bm     = allocf((size_t)NL*NCOMBO*DD);
  float* context= allocf((size_t)NBATCH*DD);
  float* Katt   = allocf((size_t)NBATCH*DD);
  float* Vatt   = allocf((size_t)NBATCH*DD);
  float* CKk    = allocf((size_t)4*NBATCH*DD);
  float* CKm    = allocf((size_t)4*NBATCH*DD);
  float* CKq    = allocf((size_t)4*NBATCH*DD);
  float* ps     = allocf((size_t)NN*4);
  float* scores = allocf((size_t)EPE*4);
  float* alphad = allocf((size_t)EPE*4);
  float* outb   = allocf((size_t)NN*DD);
  float* att    = allocf((size_t)NN);
  float* sens2  = allocf(8);
  float* rpart  = allocf((size_t)12*NBATCH*8*200);
  // bf16 buffers
  unsigned short* ak_bf   = allocb((size_t)NN*200);
  unsigned short* qv_bf   = allocb((size_t)NN*200);
  unsigned short* q_bf    = allocb((size_t)NN*200);
  unsigned short* am_bf   = allocb((size_t)NN*200);
  unsigned short* bm_bf   = allocb((size_t)NL*NCOMBO*DD);
  unsigned short* bk_bf   = allocb((size_t)NL*NCOMBO*DD);
  unsigned short* xcat_bf = allocb((size_t)NN*448);
  unsigned short* nfe_bf  = allocb((size_t)NN*224);
  unsigned short* aggr_bf = allocb((size_t)NN*224);
  unsigned short* tmp1_bf = allocb((size_t)NN*224);
  unsigned short* gelu_bf = allocb((size_t)NN*224);
  // bf16 swizzled weights
  unsigned short* wkx0  = allocb((size_t)448*256);
  unsigned short* wmx0  = allocb((size_t)448*256);
  unsigned short* wqx0  = allocb((size_t)448*256);
  unsigned short* wkN   = allocb((size_t)4*224*256);
  unsigned short* wmN   = allocb((size_t)4*224*256);
  unsigned short* wqN   = allocb((size_t)4*224*256);
  unsigned short* wm1s  = allocb((size_t)5*224*256);
  unsigned short* wm2s  = allocb((size_t)5*224*256);
  unsigned short* wqatts= allocb((size_t)224*256);
  int* sstart = alloci(NN+1);
  int* dstart = alloci(NN+1);
  int* outdeg = alloci(NN);   // outdeg..dfill contiguous -> one memset
  int* indeg  = alloci(NN);
  int* sfill  = alloci(NN);
  int* dfill  = alloci(NN);
  int* s_dst  = alloci(EPE);
  int* s_combo= alloci(EPE);
  int* d_src  = alloci(EPE);
  int* d_combo= alloci(EPE);
  int* s_dpos = alloci(EPE);
  if ((size_t)(cur-(char*)d_ws) > ws_size) return;  // insufficient scratch

  hipMemsetAsync(outdeg,0,(size_t)4*NN*4,stream);   // outdeg,indeg,sfill,dfill
  hipMemsetAsync(sens2 ,0,32,stream);

  k_noise<<<(NL*NN+255)/256,256,0,stream>>>(noise);
  k_edges<<<(EPE+255)/256,256,0,stream>>>(eidx,outdeg,indeg);
  k_scan<<<1,1024,0,stream>>>(outdeg,indeg,sstart,dstart);
  k_scatter<<<(EPE+255)/256,256,0,stream>>>(eidx,etype,ntype,sstart,dstart,sfill,dfill,
                                            s_dst,s_combo,d_src,d_combo,s_dpos);
  k_ehid<<<(NCOMBO*DD+255)/256,256,0,stream>>>(We1,be1,ehid);
  { Job j = mkjob(ehid,We2,be2,eemb,0,0,0); gemm_launch(stream,NCOMBO,DD,DD,DD,&j,1); }
  { Job js[10];
    for (int l=0;l<NL;l++){
      js[2*l+0]=mkjob(eemb, Wkey + (size_t)l*600*DD + 400*DD, 0, Bk + (size_t)l*NCOMBO*DD, 0,0,0);
      js[2*l+1]=mkjob(eemb, Wmsg + (size_t)l*600*DD + 400*DD, bmsg + (size_t)l*DD,
                      Bm + (size_t)l*NCOMBO*DD, 0,0,0);    // bmsg folded into Bm table
    }
    gemm_launch(stream,NCOMBO,DD,DD,DD,js,10);
  }
  k_cvt_flat<<<(NL*NCOMBO*DD+255)/256,256,0,stream>>>(Bm, bm_bf, NL*NCOMBO*DD);
  k_cvt_flat<<<(NL*NCOMBO*DD+255)/256,256,0,stream>>>(Bk, bk_bf, NL*NCOMBO*DD);
  // bf16 conversions
  k_cvt_xcat<<<(NN*448+255)/256,256,0,stream>>>(X,nfe,xcat_bf);
  k_cvt_nfe<<<(NN*224+255)/256,256,0,stream>>>(nfe,nfe_bf);
  { WArgs wa; int wn=0;
    auto addw=[&](const float* s, unsigned short* d, int Ks, int Kp){
      wa.j[wn].src=s; wa.j[wn].dst=d; wa.j[wn].Ksrc=Ks; wa.j[wn].Kpad=Kp; wn++; };
    addw(Wkey, wkx0, 400,448);
    addw(Wmsg, wmx0, 400,448);
    addw(Wqry, wqx0, 400,448);
    for (int l=1;l<NL;l++){
      addw(Wkey + (size_t)l*600*DD + 200*DD, wkN + (size_t)(l-1)*224*256, 200,224);
      addw(Wmsg + (size_t)l*600*DD + 200*DD, wmN + (size_t)(l-1)*224*256, 200,224);
      addw(Wqry + (size_t)l*400*DD + 200*DD, wqN + (size_t)(l-1)*224*256, 200,224);
    }
    for (int l=0;l<NL;l++){
      addw(Wm1 + (size_t)l*DD*DD, wm1s + (size_t)l*224*256, 200,224);
      addw(Wm2 + (size_t)l*DD*DD, wm2s + (size_t)l*224*256, 200,224);
    }
    addw(Wq_att, wqatts, 200,224);
    k_wswz<<<dim3(448,1,wn),256,0,stream>>>(wa);       // wn == 26
  }
  // small-M chain (K-sliced)
  { RJob j = mkrjob(hs, Wproj, bproj, context, HSZ, (size_t)SEQQ*HSZ);
    rgemm_launch(stream, &j, 1, rpart, 8, 128); }
  { RJob js[2] = { mkrjob(context, Wk_att, bk_att, Katt, DD, DD),
                   mkrjob(context, Wv_att, bv_att, Vatt, DD, DD) };
    rgemm_launch(stream, js, 2, rpart, 2, 100); }
  { RJob js[12];
    for (int l=1;l<NL;l++){
      js[3*(l-1)+0]=mkrjob(Vatt, Wkey + (size_t)l*600*DD, 0, CKk + (size_t)(l-1)*NBATCH*DD, DD, DD);
      js[3*(l-1)+1]=mkrjob(Vatt, Wmsg + (size_t)l*600*DD, 0, CKm + (size_t)(l-1)*NBATCH*DD, DD, DD);
      js[3*(l-1)+2]=mkrjob(Vatt, Wqry + (size_t)l*400*DD, 0, CKq + (size_t)(l-1)*NBATCH*DD, DD, DD);
    }
    rgemm_launch(stream, js, 12, rpart, 4, 50);
  }

  const float invs = 0.14142135623730950488f;  // 1/sqrt(50)
  for (int l=0;l<NL;l++){
    const float* bkey_l = bkey + (size_t)l*DD;
    const float* bqry_l = bqry + (size_t)l*DD;
    const unsigned short* Bk_l = bk_bf + (size_t)l*NCOMBO*DD;
    const unsigned short* Bm_l = bm_bf + (size_t)l*NCOMBO*DD;

    if (l==0){
      MJob js[3] = { mkmjob(xcat_bf, wkx0, bkey_l, 0, ak_bf, 0,0,0, 1.f,0, 200),
                     mkmjob(xcat_bf, wmx0, 0,      0, am_bf, 0,0,0, 1.f,0, 200),
                     mkmjob(xcat_bf, wqx0, bqry_l, 0, qv_bf, 0,0,0, invs,0, 200) };
      mgemm_launch(stream,448,js,3);
    } else {
      const float* ckk = CKk + (size_t)(l-1)*NBATCH*DD;
      const float* ckm = CKm + (size_t)(l-1)*NBATCH*DD;
      const float* ckq = CKq + (size_t)(l-1)*NBATCH*DD;
      MJob js[3] = { mkmjob(nfe_bf, wkN + (size_t)(l-1)*224*256, bkey_l, 0, ak_bf, att, ckk, 0, 1.f,0, 200),
                     mkmjob(nfe_bf, wmN + (size_t)(l-1)*224*256, 0,      0, am_bf, att, ckm, 0, 1.f,0, 200),
                     mkmjob(nfe_bf, wqN + (size_t)(l-1)*224*256, bqry_l, 0, qv_bf, att, ckq, 0, invs,0, 200) };
      mgemm_launch(stream,224,js,3);
    }
    k_prep<<<NN/4,256,0,stream>>>(qv_bf,ak_bf,ps);
    k_score<<<(EPE*4+255)/256,256,0,stream>>>(s_dst,s_combo,qv_bf,Bk_l,ps,scores);
    k_softmax<<<NN,64,0,stream>>>(sstart,s_dpos,scores,alphad);
    k_aggr<<<NN,256,0,stream>>>(dstart,d_src,d_combo,alphad,am_bf,Bm_l,aggr_bf);
    { MJob j = mkmjob(aggr_bf, wm1s + (size_t)l*224*256, bm1 + (size_t)l*DD, 0, tmp1_bf, 0,0,1, 1.f,0, 224);
      mgemm_launch(stream,224,&j,1); }
    { MJob j = mkmjob(tmp1_bf, wm2s + (size_t)l*224*256, bm2 + (size_t)l*DD, outb, gelu_bf, 0,0,0, 1.f,1, 224);
      mgemm_launch(stream,224,&j,1); }
    k_sens<<<64,256,0,stream>>>(outb,sens2,l);
    { MJob j = mkmjob(gelu_bf, wqatts, bq_att, 0, q_bf, 0,0,0, 1.f,0, 200);
      mgemm_launch(stream,224,&j,1); }
    k_att<<<NN/4,256,0,stream>>>(q_bf,Katt,Vatt,sens2,noise,l,att,(l==NL-1)? outp : (float*)0);
  }
}

// Round 15
// 1022.895 us; speedup vs baseline: 1.0287x; 1.0287x over previous
//
#include <hip/hip_runtime.h>
#include <stdint.h>

#define NBATCH 32
#define NNODE  400
#define NN     12800
#define NE     204800
#define EPE    217600      // NE + NN self loops
#define DD     200
#define NETYPE 38
#define NCOMBO 624         // 39*16
#define HSZ    1024
#define SEQQ   512
#define NL     5
#define ACH    128         // aggr edge-chunk staged in LDS

__device__ __forceinline__ unsigned short f2bf(float x){
  uint32_t u = __float_as_uint(x);
  uint32_t r = (u + 0x7fffu + ((u>>16)&1u)) >> 16;   // RNE
  return (unsigned short)r;
}
__device__ __forceinline__ float bf2f(unsigned short b){
  return __uint_as_float(((uint32_t)b)<<16);
}

// ---------------- threefry / noise ----------------
__device__ __forceinline__ uint32_t rotl32(uint32_t x, uint32_t d){ return (x<<d)|(x>>(32u-d)); }

__device__ void tf2x32(uint32_t k0, uint32_t k1, uint32_t x0, uint32_t x1,
                       uint32_t* o0, uint32_t* o1){
  uint32_t ks0=k0, ks1=k1, ks2=k0^k1^0x1BD11BDAu;
  uint32_t ks[3]={ks0,ks1,ks2};
  x0 += ks0; x1 += ks1;
  const uint32_t rotA[4]={13,15,26,6};
  const uint32_t rotB[4]={17,29,16,24};
  #pragma unroll
  for (int i=0;i<5;i++){
    const uint32_t* r = (i&1)? rotB : rotA;
    #pragma unroll
    for (int j=0;j<4;j++){ x0 += x1; x1 = rotl32(x1, r[j]); x1 ^= x0; }
    x0 += ks[(i+1)%3];
    x1 += ks[(i+2)%3] + (uint32_t)(i+1);
  }
  *o0=x0; *o1=x1;
}

__global__ void k_noise(float* noise){
  int i = blockIdx.x*256+threadIdx.x;
  if (i >= NL*NN) return;
  int l = i / NN, j = i % NN;
  uint32_t k0,k1,o0,o1,bits;
  tf2x32(0u,123u,0u,(uint32_t)l,&k0,&k1);          // fold_in(key(123), l)
  tf2x32(k0,k1,0u,(uint32_t)j,&o0,&o1);            // partitionable path
  bits = o0 ^ o1;
  uint32_t fb = (bits>>9) | 0x3f800000u;
  float f = __uint_as_float(fb) - 1.0f;            // [0,1)
  const float minv = -0.99999994039535522461f;     // -1 + 2^-24
  float u = fmaxf(minv, f*2.0f + minv);
  float s = (u>0.f)?1.f:((u<0.f)?-1.f:0.f);
  noise[i] = s*log1pf(-fabsf(u));
}

// ---------------- graph build ----------------
__global__ void k_edges(const int* eidx, int* outdeg, int* indeg){
  int e = blockIdx.x*256+threadIdx.x; if (e>=EPE) return;
  int s,dv;
  if (e < NE){ s = eidx[e]; dv = eidx[NE+e]; } else { s = dv = e-NE; }
  atomicAdd(&outdeg[s],1); atomicAdd(&indeg[dv],1);
}

// parallel exclusive scan (1024 threads, 13 items each; Hillis-Steele in LDS)
__global__ void k_scan(const int* outdeg, const int* indeg, int* sstart, int* dstart){
  __shared__ int buf[2][1024];
  for (int which=0; which<2; ++which){
    const int* a = which? indeg : outdeg;
    int* o = which? dstart : sstart;
    int t = threadIdx.x;
    int c0 = t*13;
    int s = 0;
    for (int i=c0;i<c0+13;i++) if (i<NN) s += a[i];
    __syncthreads();
    buf[0][t]=s; __syncthreads();
    int cur=0;
    #pragma unroll
    for (int off=1; off<1024; off<<=1){
      int v = buf[cur][t];
      if (t>=off) v += buf[cur][t-off];
      buf[cur^1][t]=v; cur^=1; __syncthreads();
    }
    int run = buf[cur][t] - s;   // exclusive prefix
    for (int i=c0;i<c0+13;i++) if (i<NN){ o[i]=run; run+=a[i]; }
    if (t==0) o[NN]=EPE;
  }
}

__global__ void k_scatter(const int* eidx, const int* etype, const int* ntype,
                          const int* sstart, const int* dstart, int* sfill, int* dfill,
                          int* s_dst, int* s_combo, int* d_src, int* d_combo, int* s_dpos){
  int e = blockIdx.x*256+threadIdx.x; if (e>=EPE) return;
  int s,dv,et;
  if (e<NE){ s=eidx[e]; dv=eidx[NE+e]; et=etype[e]; } else { s=dv=e-NE; et=NETYPE; }
  int c = et*16 + ntype[s]*4 + ntype[dv];
  int p = sstart[s] + atomicAdd(&sfill[s],1);
  s_dst[p]=dv; s_combo[p]=c;
  int q = dstart[dv] + atomicAdd(&dfill[dv],1);
  d_src[q]=s; d_combo[q]=c; s_dpos[p]=q;
}

// ---------------- edge encoder hidden (one-hot -> rows of We1) ----------------
__global__ void k_ehid(const float* We1, const float* be1, float* ehid){
  int i = blockIdx.x*256+threadIdx.x; if (i>=NCOMBO*DD) return;
  int c = i/DD, d = i%DD;
  int et=c>>4, ht=(c>>2)&3, tt=c&3;
  float v = We1[et*DD+d] + We1[(39+ht)*DD+d] + We1[(43+tt)*DD+d] + be1[d];
  ehid[i] = fmaxf(v,0.f);
}

// ---------------- bf16 A-matrix conversions, K-major swizzled [(k/8)][NN][8] ----------------
__global__ void k_cvt_xcat(const float* X, const float* nfe, unsigned short* xbf){
  int i=blockIdx.x*256+threadIdx.x; if (i>=NN*448) return;
  int n=i/448, d=i%448;
  float v = (d<200)? X[(size_t)n*200+d] : (d<400)? nfe[(size_t)n*200+(d-200)] : 0.f;
  xbf[(((size_t)(d>>3))*NN + n)*8 + (d&7)] = f2bf(v);
}
__global__ void k_cvt_nfe(const float* nfe, unsigned short* nbf){
  int i=blockIdx.x*256+threadIdx.x; if (i>=NN*224) return;
  int n=i/224, d=i%224;
  nbf[(((size_t)(d>>3))*NN + n)*8 + (d&7)] = (d<200)? f2bf(nfe[(size_t)n*200+d]) : 0;
}
// fp32 -> bf16 flat copy (row-major tables)
__global__ void k_cvt_flat(const float* src, unsigned short* dst, int n){
  int i=blockIdx.x*256+threadIdx.x; if (i>=n) return;
  dst[i] = f2bf(src[i]);
}

// ---------------- weight swizzle: fp32 [Ksrc x 200] -> bf16 [(Kpad/8) x 256 x 8] ----------------
struct WJob { const float* src; unsigned short* dst; int Ksrc; int Kpad; };
struct WArgs { WJob j[26]; };
__global__ void k_wswz(WArgs a){
  WJob jb = a.j[blockIdx.z];
  int i = blockIdx.x*256+threadIdx.x;
  if (i >= jb.Kpad*256) return;
  int k = i>>8, n = i&255;
  unsigned short v = 0;
  if (k<jb.Ksrc && n<200) v = f2bf(jb.src[(size_t)k*200+n]);
  jb.dst[(((size_t)(k>>3))*256 + n)*8 + (k&7)] = v;
}

typedef __attribute__((ext_vector_type(8))) short bf16x8;
typedef __attribute__((ext_vector_type(4))) float f32x4;

// ---------------- MFMA bf16 GEMM: C = A(swz [(k/8)][NN][8]) @ B(swz,Kp x 256) ----------------
// K-major A: an A-frag load is 4 runs of 256B (16 consecutive rows x 16B) vs 16
// fragmented 64B lines row-major. Runtime-K loop (round-13 form; full unroll
// regressed: +12 VGPR -> occupancy 33->27%). XCD-aware 1D grid as before.
// Cbf: cbf_swz=1 -> K-major swizzled output (feeds next mgemm A), else row-major 200.
struct MJob { const unsigned short* A; const unsigned short* B; const float* bias;
              float* C; unsigned short* Cbf; const float* r1v; const float* r1m;
              int relu; float scale; int gelu; int cbf_swz; };
struct MArgs { int Kp; int nj; MJob j[3]; };

__global__ __launch_bounds__(256) void k_mgemm(MArgs g){
  const int G = 4*g.nj;
  int bid = blockIdx.x;
  int xcd = bid & 7;
  int t   = bid >> 3;
  int grp = t % G;
  int yhi = t / G;
  int y   = xcd + 8*yhi;
  if (y >= 100) return;
  const int ni = grp & 3;
  const int zi = grp >> 2;
  const MJob jb = g.j[zi];
  const int lane = threadIdx.x&63, w = threadIdx.x>>6;
  const int lr = lane&15, lk = lane>>4;
  const int m0 = y*128 + w*32;
  const int n0 = ni*64;
  const int Kp = g.Kp;
  f32x4 acc[2][4] = {};
  const unsigned short* a0 = jb.A + ((size_t)lk*NN + m0 + lr)*8;        // chunk lk, row m0+lr
  const unsigned short* a1 = a0 + (size_t)16*8;                        // +16 rows
  const size_t astep = (size_t)4*NN*8;                                 // +4 chunks (ks+=32)
  for (int ks=0; ks<Kp; ks+=32){
    size_t ao = (size_t)(ks>>3>>2)*astep;   // (ks/32)*astep
    bf16x8 af0 = *(const bf16x8*)(a0 + ao);
    bf16x8 af1 = *(const bf16x8*)(a1 + ao);
    const unsigned short* bb = jb.B + (((size_t)(ks>>3) + lk)*256 + n0 + lr)*8;
    bf16x8 b0 = *(const bf16x8*)(bb);
    bf16x8 b1 = *(const bf16x8*)(bb + 128);
    bf16x8 b2 = *(const bf16x8*)(bb + 256);
    bf16x8 b3 = *(const bf16x8*)(bb + 384);
    acc[0][0]=__builtin_amdgcn_mfma_f32_16x16x32_bf16(af0,b0,acc[0][0],0,0,0);
    acc[0][1]=__builtin_amdgcn_mfma_f32_16x16x32_bf16(af0,b1,acc[0][1],0,0,0);
    acc[0][2]=__builtin_amdgcn_mfma_f32_16x16x32_bf16(af0,b2,acc[0][2],0,0,0);
    acc[0][3]=__builtin_amdgcn_mfma_f32_16x16x32_bf16(af0,b3,acc[0][3],0,0,0);
    acc[1][0]=__builtin_amdgcn_mfma_f32_16x16x32_bf16(af1,b0,acc[1][0],0,0,0);
    acc[1][1]=__builtin_amdgcn_mfma_f32_16x16x32_bf16(af1,b1,acc[1][1],0,0,0);
    acc[1][2]=__builtin_amdgcn_mfma_f32_16x16x32_bf16(af1,b2,acc[1][2],0,0,0);
    acc[1][3]=__builtin_amdgcn_mfma_f32_16x16x32_bf16(af1,b3,acc[1][3],0,0,0);
  }
  #pragma unroll
  for (int mt=0; mt<2; ++mt){
    int mbase = m0 + mt*16 + lk*4;
    #pragma unroll
    for (int nt=0; nt<4; ++nt){
      int n = n0 + nt*16 + lr;
      #pragma unroll
      for (int r=0;r<4;r++){
        int m = mbase + r;
        float v = acc[mt][nt][r];
        if (n < 200){
          if (jb.r1v)  v += jb.r1v[m]*jb.r1m[(size_t)(m/NNODE)*200 + n];
          if (jb.bias) v += jb.bias[n];
          v *= jb.scale;
          if (jb.relu) v = fmaxf(v, 0.f);
          if (jb.C)    jb.C[(size_t)m*200 + n] = v;
          if (jb.Cbf){
            float o = jb.gelu? 0.5f*v*(1.0f+erff(v*0.70710678118654752440f)) : v;
            if (jb.cbf_swz) jb.Cbf[(((size_t)(n>>3))*NN + m)*8 + (n&7)] = f2bf(o);
            else            jb.Cbf[(size_t)m*200 + n] = f2bf(o);
          }
        } else if (jb.Cbf && jb.cbf_swz && n < 224){
          jb.Cbf[(((size_t)(n>>3))*NN + m)*8 + (n&7)] = 0;
        }
      }
    }
  }
}

// ---------------- small-M fp32 GEMM, K-sliced: part + reduce ----------------
struct RJob { const float* A; const float* W; const float* bias; float* C; int K; size_t lda; };
struct RArgs { RJob j[12]; float* part; int NS; int Kc; };
__global__ __launch_bounds__(256) void k_rowpart(RArgs a){
  RJob jb = a.j[blockIdx.z];
  int m = blockIdx.x, s = blockIdx.y;
  int k0 = s*a.Kc, k1 = k0 + a.Kc; if (k1 > jb.K) k1 = jb.K;
  int kc = k1 - k0;
  __shared__ float row[128];
  const float* ap = jb.A + (size_t)m*jb.lda + k0;
  for (int k=threadIdx.x; k<kc; k+=256) row[k]=ap[k];
  __syncthreads();
  int n = threadIdx.x;
  if (n < 200){
    float acc = 0.f;
    const float* wp = jb.W + (size_t)k0*200 + n;
    for (int kk=0; kk<kc; ++kk) acc += row[kk]*wp[(size_t)kk*200];
    a.part[(((size_t)blockIdx.z*32 + m)*8 + s)*200 + n] = acc;
  }
}
__global__ __launch_bounds__(256) void k_rowred(RArgs a){
  RJob jb = a.j[blockIdx.z];
  int m = blockIdx.x, n = threadIdx.x;
  if (n >= 200) return;
  float acc = jb.bias? jb.bias[n] : 0.f;
  for (int s=0; s<a.NS; ++s) acc += a.part[(((size_t)blockIdx.z*32 + m)*8 + s)*200 + n];
  jb.C[(size_t)m*200+n] = acc;
}

// ---------------- generic fp32 GEMM (M=624 edge-table jobs) ----------------
struct Job {
  const float* A; const float* W; const float* bias; float* C;
  const float* r1v; const float* r1m; int relu;
};
struct GArgs { int M,N,K,lda; Job j[12]; };

#define BMT 64
#define BNT 64
#define BKT 16

__global__ __launch_bounds__(256) void k_gemm(GArgs g){
  const Job jb = g.j[blockIdx.z];
  const int m0 = blockIdx.y*BMT, n0 = blockIdx.x*BNT;
  __shared__ float As[BKT][BMT+4];
  __shared__ float Bs[BKT][BNT+4];
  float acc[4][4]={};
  const int t = threadIdx.x;
  const int tx = t & 15, ty = t >> 4;
  for (int k0=0; k0<g.K; k0+=BKT){
    {
      int r = t>>2, cq = t&3;
      int m = m0+r, k = k0+cq*4;
      float4 v = make_float4(0.f,0.f,0.f,0.f);
      if (m < g.M && k < g.K){
        if (k+3 < g.K) v = *(const float4*)(jb.A + (size_t)m*g.lda + k);
        else {
          const float* ap = jb.A + (size_t)m*g.lda;
          float tm[4]={0.f,0.f,0.f,0.f};
          for (int qq=0;qq<4;qq++) if (k+qq<g.K) tm[qq]=ap[k+qq];
          v = make_float4(tm[0],tm[1],tm[2],tm[3]);
        }
      }
      As[cq*4+0][r]=v.x; As[cq*4+1][r]=v.y; As[cq*4+2][r]=v.z; As[cq*4+3][r]=v.w;
    }
    {
      int r = t>>4, cq = t&15;
      int k = k0+r, n = n0+cq*4;
      float4 v = make_float4(0.f,0.f,0.f,0.f);
      if (k < g.K && n < g.N){
        if (n+3 < g.N) v = *(const float4*)(jb.W + (size_t)k*g.N + n);
        else { const float* wp = jb.W + (size_t)k*g.N;
          float tm[4]={0.f,0.f,0.f,0.f};
          for (int qq=0;qq<4;qq++) if (n+qq<g.N) tm[qq]=wp[n+qq];
          v = make_float4(tm[0],tm[1],tm[2],tm[3]); }
      }
      Bs[r][cq*4+0]=v.x; Bs[r][cq*4+1]=v.y; Bs[r][cq*4+2]=v.z; Bs[r][cq*4+3]=v.w;
    }
    __syncthreads();
    int kend = g.K-k0; if (kend>BKT) kend=BKT;
    for (int kk=0;kk<kend;kk++){
      float4 av = *(const float4*)&As[kk][ty*4];
      float4 bv = *(const float4*)&Bs[kk][tx*4];
      float a[4]={av.x,av.y,av.z,av.w};
      float b[4]={bv.x,bv.y,bv.z,bv.w};
      #pragma unroll
      for (int i=0;i<4;i++){
        #pragma unroll
        for (int jq=0;jq<4;jq++) acc[i][jq] += a[i]*b[jq];
      }
    }
    __syncthreads();
  }
  #pragma unroll
  for (int i=0;i<4;i++){
    int m = m0+ty*4+i; if (m>=g.M) continue;
    int bidx = m / NNODE;
    #pragma unroll
    for (int jq=0;jq<4;jq++){
      int n = n0+tx*4+jq; if (n>=g.N) continue;
      float v = acc[i][jq];
      if (jb.bias) v += jb.bias[n];
      if (jb.r1v)  v += jb.r1v[m]*jb.r1m[(size_t)bidx*g.N + n];
      if (jb.relu) v = fmaxf(v,0.f);
      jb.C[(size_t)m*g.N+n] = v;
    }
  }
}

// ---------------- per-node prep: ps[h] = sum_d qv*ak (bf16 row-major tables) ----------------
__global__ void k_prep(const unsigned short* qv, const unsigned short* ak, float* ps){
  int wid = threadIdx.x>>6, lane = threadIdx.x&63;
  int n = blockIdx.x*4 + wid; if (n>=NN) return;
  float acch[4]={0.f,0.f,0.f,0.f};
  if (lane < 25){
    bf16x8 q = *(const bf16x8*)(qv + (size_t)n*200 + lane*8);
    bf16x8 a = *(const bf16x8*)(ak + (size_t)n*200 + lane*8);
    #pragma unroll
    for (int j=0;j<8;j++){
      int d = lane*8+j;
      int hd = (d>=50)+(d>=100)+(d>=150);
      float p = bf2f((unsigned short)q[j])*bf2f((unsigned short)a[j]);
      #pragma unroll
      for (int h=0;h<4;h++) acch[h] += (hd==h)? p : 0.f;
    }
  }
  for (int off=1; off<64; off<<=1){
    #pragma unroll
    for (int h=0;h<4;h++) acch[h] += __shfl_xor(acch[h], off);
  }
  if (lane==0){
    #pragma unroll
    for (int h=0;h<4;h++) ps[n*4+h]=acch[h];
  }
}

// ---------------- per-edge scores: 4 lanes per edge, bf16 qv/Bk gathers ----------------
__global__ __launch_bounds__(256) void k_score(const int* s_dst, const int* s_combo,
                        const unsigned short* qv, const unsigned short* Bk,
                        const float* ps, float* scores){
  int p = blockIdx.x*64 + (threadIdx.x>>2);
  if (p>=EPE) return;
  int sub = threadIdx.x&3;
  int dv = s_dst[p], c = s_combo[p];
  const unsigned short* qr = qv + (size_t)dv*200;
  const unsigned short* br = Bk + (size_t)c*200;
  float acc[4]={0.f,0.f,0.f,0.f};
  #pragma unroll
  for (int i=0;i<7;i++){
    int ch = sub + 4*i;
    if (ch < 25){
      bf16x8 q = *(const bf16x8*)(qr + ch*8);
      bf16x8 b = *(const bf16x8*)(br + ch*8);
      #pragma unroll
      for (int j=0;j<8;j++){
        int d = ch*8+j;
        int hd = (d>=50)+(d>=100)+(d>=150);
        float pr = bf2f((unsigned short)q[j])*bf2f((unsigned short)b[j]);
        #pragma unroll
        for (int h=0;h<4;h++) acc[h] += (hd==h)? pr : 0.f;
      }
    }
  }
  #pragma unroll
  for (int off=1; off<4; off<<=1){
    #pragma unroll
    for (int h=0;h<4;h++) acc[h] += __shfl_xor(acc[h], off);
  }
  scores[(size_t)p*4+sub] = ps[dv*4+sub] + acc[sub];
}

// ---------------- segment softmax over src; alpha scattered to dst-order ----------------
__global__ void k_softmax(const int* sstart, const int* s_dpos, const float* scores, float* alpha_d){
  int n = blockIdx.x;
  int st = sstart[n], en = sstart[n+1];
  int cnt = en-st;
  int t = threadIdx.x;
  float mx = -3.402823466e38f;
  for (int i=t; i<cnt*4; i+=64) mx = fmaxf(mx, scores[(size_t)(st+(i>>2))*4 + (i&3)]);
  for (int off=4; off<64; off<<=1) mx = fmaxf(mx, __shfl_xor(mx,off));
  float sm=0.f;
  for (int i=t; i<cnt*4; i+=64) sm += expf(scores[(size_t)(st+(i>>2))*4 + (i&3)] - mx);
  for (int off=4; off<64; off<<=1) sm += __shfl_xor(sm,off);
  float scale = (float)cnt / (sm + 1e-16f);
  for (int i=t; i<cnt*4; i+=64){
    int p = st+(i>>2), h = i&3;
    float a = expf(scores[(size_t)p*4+h]-mx)*scale;
    alpha_d[(size_t)s_dpos[p]*4+h] = a;
  }
}

// ---------------- aggregate to dst: LDS-staged, 4 waves/node; K-major swz output ----------------
__global__ __launch_bounds__(256) void k_aggr(const int* dstart, const int* d_src, const int* d_combo,
                       const float* alpha_d,
                       const unsigned short* Am, const unsigned short* Bm,
                       unsigned short* aggr_bf){
  __shared__ float red[4][200];
  __shared__ float s_al[ACH*4];
  __shared__ int   s_s[ACH], s_c[ACH];
  int v = blockIdx.x;
  int w = threadIdx.x>>6, lane = threadIdx.x&63;
  int st=dstart[v], en=dstart[v+1];
  float acc[8]={0.f,0.f,0.f,0.f,0.f,0.f,0.f,0.f};
  int h[8];
  #pragma unroll
  for (int j=0;j<8;j++) h[j] = (lane*8+j)/50;     // valid for lane<25
  for (int c0=st; c0<en; c0+=ACH){
    int cnt = en-c0; if (cnt>ACH) cnt=ACH;
    __syncthreads();
    for (int i=threadIdx.x; i<cnt; i+=256){ s_s[i]=d_src[c0+i]; s_c[i]=d_combo[c0+i]; }
    for (int i=threadIdx.x; i<cnt*4; i+=256){ s_al[i]=alpha_d[(size_t)c0*4+i]; }
    __syncthreads();
    if (lane < 25){
      for (int q=w; q<cnt; q+=4){
        int s=s_s[q], c=s_c[q];
        bf16x8 am = *(const bf16x8*)(Am + (size_t)s*200 + lane*8);
        bf16x8 bm = *(const bf16x8*)(Bm + (size_t)c*200 + lane*8);
        #pragma unroll
        for (int j=0;j<8;j++){
          float a = s_al[q*4+h[j]];
          acc[j] += a*(bf2f((unsigned short)am[j]) + bf2f((unsigned short)bm[j]));
        }
      }
    }
  }
  if (lane < 25){
    #pragma unroll
    for (int j=0;j<8;j++) red[w][lane*8+j]=acc[j];
  }
  __syncthreads();
  int d = threadIdx.x;
  if (d < 200){
    float r = red[0][d]+red[1][d]+red[2][d]+red[3][d];
    aggr_bf[(((size_t)(d>>3))*NN + v)*8 + (d&7)] = f2bf(r);
  } else if (d < 224){
    aggr_bf[(((size_t)(d>>3))*NN + v)*8 + (d&7)] = 0;
  }
}

// ---------------- sensitivity: max ||out||^2 ----------------
__global__ void k_sens(const float* out, float* sens2, int l){
  __shared__ float smax[4];
  int wid = threadIdx.x>>6, lane = threadIdx.x&63;
  int gw = blockIdx.x*4 + wid;
  float mx = 0.f;
  for (int n = gw; n < NN; n += 256){
    const float4* row = (const float4*)(out + (size_t)n*DD);
    float ss = 0.f;
    if (lane < 50){ float4 v = row[lane]; ss = v.x*v.x + v.y*v.y + v.z*v.z + v.w*v.w; }
    for (int off=1; off<64; off<<=1) ss += __shfl_xor(ss, off);
    mx = fmaxf(mx, ss);
  }
  if (lane==0) smax[wid] = mx;
  __syncthreads();
  if (threadIdx.x==0){
    float m = fmaxf(fmaxf(smax[0],smax[1]),fmaxf(smax[2],smax[3]));
    atomicMax((int*)&sens2[l], __float_as_int(m));
  }
}

// ---------------- attention (Q in bf16 row-major) ----------------
__global__ void k_att(const unsigned short* Qb, const float* Katt, const float* Vatt,
                      const float* sens2, const float* noise, int l,
                      float* att, float* outX){
  int wid=threadIdx.x>>6, lane=threadIdx.x&63;
  int n=blockIdx.x*4+wid; if (n>=NN) return;
  int b=n/NNODE;
  float qq=0.f, qk=0.f;
  for (int d=lane; d<DD; d+=64){
    float q=bf2f(Qb[(size_t)n*200+d]);
    qq += q*q; qk += q*Katt[b*DD+d];
  }
  for (int off=1;off<64;off<<=1){ qq+=__shfl_xor(qq,off); qk+=__shfl_xor(qk,off); }
  float nrm = fmaxf(sqrtf(qq), 1e-12f);
  float a = (qk/nrm) * 0.07071067811865475244f;    // 1/sqrt(200)
  a += 4.0f*sqrtf(sens2[l]) * noise[(size_t)l*NN + n];
  if (lane==0) att[n]=a;
  if (outX){
    for (int d=lane; d<DD; d+=64) outX[(size_t)n*DD+d] = a*Vatt[b*DD+d];
  }
}

// ---------------- host ----------------
static inline Job mkjob(const float* A, const float* W, const float* bias, float* C,
                        const float* r1v, const float* r1m, int relu){
  Job j; j.A=A; j.W=W; j.bias=bias; j.C=C; j.r1v=r1v; j.r1m=r1m; j.relu=relu; return j;
}

static inline void gemm_launch(hipStream_t stream, int M,int N,int K,int lda,
                               const Job* jobs, int nj){
  GArgs g; g.M=M; g.N=N; g.K=K; g.lda=lda;
  for (int i=0;i<nj;i++) g.j[i]=jobs[i];
  for (int i=nj;i<12;i++) g.j[i]=jobs[0];
  dim3 grid((N+BNT-1)/BNT,(M+BMT-1)/BMT,nj);
  k_gemm<<<grid,256,0,stream>>>(g);
}

static inline RJob mkrjob(const float* A, const float* W, const float* bias, float* C,
                          int K, size_t lda){
  RJob j; j.A=A; j.W=W; j.bias=bias; j.C=C; j.K=K; j.lda=lda; return j;
}

static inline void rgemm_launch(hipStream_t stream, const RJob* jobs, int nj,
                                float* part, int NS, int Kc){
  RArgs a;
  for (int i=0;i<nj;i++) a.j[i]=jobs[i];
  for (int i=nj;i<12;i++) a.j[i]=jobs[0];
  a.part = part; a.NS = NS; a.Kc = Kc;
  k_rowpart<<<dim3(NBATCH,NS,nj),256,0,stream>>>(a);
  k_rowred <<<dim3(NBATCH,1,nj),256,0,stream>>>(a);
}

static inline MJob mkmjob(const unsigned short* A, const unsigned short* B, const float* bias,
                          float* C, unsigned short* Cbf, const float* r1v, const float* r1m,
                          int relu, float scale, int gelu, int cbf_swz){
  MJob j; j.A=A; j.B=B; j.bias=bias; j.C=C; j.Cbf=Cbf; j.r1v=r1v; j.r1m=r1m;
  j.relu=relu; j.scale=scale; j.gelu=gelu; j.cbf_swz=cbf_swz; return j;
}

static inline void mgemm_launch(hipStream_t stream, int Kpad, const MJob* jobs, int nj){
  MArgs a; a.Kp=Kpad; a.nj=nj;
  for (int i=0;i<nj;i++) a.j[i]=jobs[i];
  for (int i=nj;i<3;i++) a.j[i]=jobs[0];
  int nblk = 8 * (4*nj) * 13;   // y groups of 8, 13 groups cover y<100
  k_mgemm<<<nblk,256,0,stream>>>(a);
}

extern "C" void kernel_launch(void* const* d_in, const int* in_sizes, int n_in,
                              void* d_out, int out_size, void* d_ws, size_t ws_size,
                              hipStream_t stream){
  const float* hs    = (const float*)d_in[0];
  const float* X     = (const float*)d_in[1];
  const float* nfe   = (const float*)d_in[2];
  const int*   eidx  = (const int*)d_in[3];
  const int*   etype = (const int*)d_in[4];
  const int*   ntype = (const int*)d_in[5];
  const float* We1   = (const float*)d_in[7];
  const float* be1   = (const float*)d_in[8];
  const float* We2   = (const float*)d_in[9];
  const float* be2   = (const float*)d_in[10];
  const float* Wkey  = (const float*)d_in[11];
  const float* bkey  = (const float*)d_in[12];
  const float* Wmsg  = (const float*)d_in[13];
  const float* bmsg  = (const float*)d_in[14];
  const float* Wqry  = (const float*)d_in[15];
  const float* bqry  = (const float*)d_in[16];
  const float* Wm1   = (const float*)d_in[17];
  const float* bm1   = (const float*)d_in[18];
  const float* Wm2   = (const float*)d_in[19];
  const float* bm2   = (const float*)d_in[20];
  const float* Wq_att= (const float*)d_in[21];
  const float* bq_att= (const float*)d_in[22];
  const float* Wk_att= (const float*)d_in[23];
  const float* bk_att= (const float*)d_in[24];
  const float* Wv_att= (const float*)d_in[25];
  const float* bv_att= (const float*)d_in[26];
  const float* Wproj = (const float*)d_in[27];
  const float* bproj = (const float*)d_in[28];
  float* outp = (float*)d_out;

  char* cur = (char*)d_ws;
  auto allocf = [&](size_t n)->float*{ float* p=(float*)cur; cur += ((n*4+255)/256)*256; return p; };
  auto alloci = [&](size_t n)->int*  { int*   p=(int*)cur;   cur += ((n*4+255)/256)*256; return p; };
  auto allocb = [&](size_t n)->unsigned short*{ unsigned short* p=(unsigned short*)cur; cur += ((n*2+255)/256)*256; return p; };

  float* noise  = allocf((size_t)NL*NN);
  float* ehid   = allocf((size_t)NCOMBO*DD);
  float* eemb   = allocf((size_t)NCOMBO*DD);
  float* Bk     = allocf((size_t)NL*NCOMBO*DD);
  float* Bm     = allocf((size_t)NL*NCOMBO*DD);
  float* context= allocf((size_t)NBATCH*DD);
  float* Katt   = allocf((size_t)NBATCH*DD);
  float* Vatt   = allocf((size_t)NBATCH*DD);
  float* CKk    = allocf((size_t)4*NBATCH*DD);
  float* CKm    = allocf((size_t)4*NBATCH*DD);
  float* CKq    = allocf((size_t)4*NBATCH*DD);
  float* ps     = allocf((size_t)NN*4);
  float* scores = allocf((size_t)EPE*4);
  float* alphad = allocf((size_t)EPE*4);
  float* outb   = allocf((size_t)NN*DD);
  float* att    = allocf((size_t)NN);
  float* sens2  = allocf(8);
  float* rpart  = allocf((size_t)12*NBATCH*8*200);
  // bf16 buffers (row-major edge tables)
  unsigned short* ak_bf   = allocb((size_t)NN*200);
  unsigned short* qv_bf   = allocb((size_t)NN*200);
  unsigned short* q_bf    = allocb((size_t)NN*200);
  unsigned short* am_bf   = allocb((size_t)NN*200);
  unsigned short* bm_bf   = allocb((size_t)NL*NCOMBO*DD);
  unsigned short* bk_bf   = allocb((size_t)NL*NCOMBO*DD);
  // K-major swizzled A buffers [(k/8)][NN][8]
  unsigned short* xcat_bf = allocb((size_t)NN*448);
  unsigned short* nfe_bf  = allocb((size_t)NN*224);
  unsigned short* aggr_bf = allocb((size_t)NN*224);
  unsigned short* tmp1_bf = allocb((size_t)NN*224);
  unsigned short* gelu_bf = allocb((size_t)NN*224);
  // bf16 swizzled weights
  unsigned short* wkx0  = allocb((size_t)448*256);
  unsigned short* wmx0  = allocb((size_t)448*256);
  unsigned short* wqx0  = allocb((size_t)448*256);
  unsigned short* wkN   = allocb((size_t)4*224*256);
  unsigned short* wmN   = allocb((size_t)4*224*256);
  unsigned short* wqN   = allocb((size_t)4*224*256);
  unsigned short* wm1s  = allocb((size_t)5*224*256);
  unsigned short* wm2s  = allocb((size_t)5*224*256);
  unsigned short* wqatts= allocb((size_t)224*256);
  int* sstart = alloci(NN+1);
  int* dstart = alloci(NN+1);
  int* outdeg = alloci(NN);   // outdeg..dfill contiguous -> one memset
  int* indeg  = alloci(NN);
  int* sfill  = alloci(NN);
  int* dfill  = alloci(NN);
  int* s_dst  = alloci(EPE);
  int* s_combo= alloci(EPE);
  int* d_src  = alloci(EPE);
  int* d_combo= alloci(EPE);
  int* s_dpos = alloci(EPE);
  if ((size_t)(cur-(char*)d_ws) > ws_size) return;  // insufficient scratch

  hipMemsetAsync(outdeg,0,(size_t)4*NN*4,stream);   // outdeg,indeg,sfill,dfill
  hipMemsetAsync(sens2 ,0,32,stream);

  k_noise<<<(NL*NN+255)/256,256,0,stream>>>(noise);
  k_edges<<<(EPE+255)/256,256,0,stream>>>(eidx,outdeg,indeg);
  k_scan<<<1,1024,0,stream>>>(outdeg,indeg,sstart,dstart);
  k_scatter<<<(EPE+255)/256,256,0,stream>>>(eidx,etype,ntype,sstart,dstart,sfill,dfill,
                                            s_dst,s_combo,d_src,d_combo,s_dpos);
  k_ehid<<<(NCOMBO*DD+255)/256,256,0,stream>>>(We1,be1,ehid);
  { Job j = mkjob(ehid,We2,be2,eemb,0,0,0); gemm_launch(stream,NCOMBO,DD,DD,DD,&j,1); }
  { Job js[10];
    for (int l=0;l<NL;l++){
      js[2*l+0]=mkjob(eemb, Wkey + (size_t)l*600*DD + 400*DD, 0, Bk + (size_t)l*NCOMBO*DD, 0,0,0);
      js[2*l+1]=mkjob(eemb, Wmsg + (size_t)l*600*DD + 400*DD, bmsg + (size_t)l*DD,
                      Bm + (size_t)l*NCOMBO*DD, 0,0,0);    // bmsg folded into Bm table
    }
    gemm_launch(stream,NCOMBO,DD,DD,DD,js,10);
  }
  k_cvt_flat<<<(NL*NCOMBO*DD+255)/256,256,0,stream>>>(Bm, bm_bf, NL*NCOMBO*DD);
  k_cvt_flat<<<(NL*NCOMBO*DD+255)/256,256,0,stream>>>(Bk, bk_bf, NL*NCOMBO*DD);
  // K-major bf16 conversions
  k_cvt_xcat<<<(NN*448+255)/256,256,0,stream>>>(X,nfe,xcat_bf);
  k_cvt_nfe<<<(NN*224+255)/256,256,0,stream>>>(nfe,nfe_bf);
  { WArgs wa; int wn=0;
    auto addw=[&](const float* s, unsigned short* d, int Ks, int Kp){
      wa.j[wn].src=s; wa.j[wn].dst=d; wa.j[wn].Ksrc=Ks; wa.j[wn].Kpad=Kp; wn++; };
    addw(Wkey, wkx0, 400,448);
    addw(Wmsg, wmx0, 400,448);
    addw(Wqry, wqx0, 400,448);
    for (int l=1;l<NL;l++){
      addw(Wkey + (size_t)l*600*DD + 200*DD, wkN + (size_t)(l-1)*224*256, 200,224);
      addw(Wmsg + (size_t)l*600*DD + 200*DD, wmN + (size_t)(l-1)*224*256, 200,224);
      addw(Wqry + (size_t)l*400*DD + 200*DD, wqN + (size_t)(l-1)*224*256, 200,224);
    }
    for (int l=0;l<NL;l++){
      addw(Wm1 + (size_t)l*DD*DD, wm1s + (size_t)l*224*256, 200,224);
      addw(Wm2 + (size_t)l*DD*DD, wm2s + (size_t)l*224*256, 200,224);
    }
    addw(Wq_att, wqatts, 200,224);
    k_wswz<<<dim3(448,1,wn),256,0,stream>>>(wa);       // wn == 26
  }
  // small-M chain (K-sliced)
  { RJob j = mkrjob(hs, Wproj, bproj, context, HSZ, (size_t)SEQQ*HSZ);
    rgemm_launch(stream, &j, 1, rpart, 8, 128); }
  { RJob js[2] = { mkrjob(context, Wk_att, bk_att, Katt, DD, DD),
                   mkrjob(context, Wv_att, bv_att, Vatt, DD, DD) };
    rgemm_launch(stream, js, 2, rpart, 2, 100); }
  { RJob js[12];
    for (int l=1;l<NL;l++){
      js[3*(l-1)+0]=mkrjob(Vatt, Wkey + (size_t)l*600*DD, 0, CKk + (size_t)(l-1)*NBATCH*DD, DD, DD);
      js[3*(l-1)+1]=mkrjob(Vatt, Wmsg + (size_t)l*600*DD, 0, CKm + (size_t)(l-1)*NBATCH*DD, DD, DD);
      js[3*(l-1)+2]=mkrjob(Vatt, Wqry + (size_t)l*400*DD, 0, CKq + (size_t)(l-1)*NBATCH*DD, DD, DD);
    }
    rgemm_launch(stream, js, 12, rpart, 4, 50);
  }

  const float invs = 0.14142135623730950488f;  // 1/sqrt(50)
  for (int l=0;l<NL;l++){
    const float* bkey_l = bkey + (size_t)l*DD;
    const float* bqry_l = bqry + (size_t)l*DD;
    const unsigned short* Bk_l = bk_bf + (size_t)l*NCOMBO*DD;
    const unsigned short* Bm_l = bm_bf + (size_t)l*NCOMBO*DD;

    if (l==0){
      MJob js[3] = { mkmjob(xcat_bf, wkx0, bkey_l, 0, ak_bf, 0,0,0, 1.f,0, 0),
                     mkmjob(xcat_bf, wmx0, 0,      0, am_bf, 0,0,0, 1.f,0, 0),
                     mkmjob(xcat_bf, wqx0, bqry_l, 0, qv_bf, 0,0,0, invs,0, 0) };
      mgemm_launch(stream,448,js,3);
    } else {
      const float* ckk = CKk + (size_t)(l-1)*NBATCH*DD;
      const float* ckm = CKm + (size_t)(l-1)*NBATCH*DD;
      const float* ckq = CKq + (size_t)(l-1)*NBATCH*DD;
      MJob js[3] = { mkmjob(nfe_bf, wkN + (size_t)(l-1)*224*256, bkey_l, 0, ak_bf, att, ckk, 0, 1.f,0, 0),
                     mkmjob(nfe_bf, wmN + (size_t)(l-1)*224*256, 0,      0, am_bf, att, ckm, 0, 1.f,0, 0),
                     mkmjob(nfe_bf, wqN + (size_t)(l-1)*224*256, bqry_l, 0, qv_bf, att, ckq, 0, invs,0, 0) };
      mgemm_launch(stream,224,js,3);
    }
    k_prep<<<NN/4,256,0,stream>>>(qv_bf,ak_bf,ps);
    k_score<<<(EPE*4+255)/256,256,0,stream>>>(s_dst,s_combo,qv_bf,Bk_l,ps,scores);
    k_softmax<<<NN,64,0,stream>>>(sstart,s_dpos,scores,alphad);
    k_aggr<<<NN,256,0,stream>>>(dstart,d_src,d_combo,alphad,am_bf,Bm_l,aggr_bf);
    { MJob j = mkmjob(aggr_bf, wm1s + (size_t)l*224*256, bm1 + (size_t)l*DD, 0, tmp1_bf, 0,0,1, 1.f,0, 1);
      mgemm_launch(stream,224,&j,1); }
    { MJob j = mkmjob(tmp1_bf, wm2s + (size_t)l*224*256, bm2 + (size_t)l*DD, outb, gelu_bf, 0,0,0, 1.f,1, 1);
      mgemm_launch(stream,224,&j,1); }
    k_sens<<<64,256,0,stream>>>(outb,sens2,l);
    { MJob j = mkmjob(gelu_bf, wqatts, bq_att, 0, q_bf, 0,0,0, 1.f,0, 0);
      mgemm_launch(stream,224,&j,1); }
    k_att<<<NN/4,256,0,stream>>>(q_bf,Katt,Vatt,sens2,noise,l,att,(l==NL-1)? outp : (float*)0);
  }
}